// Round 4
// baseline (490.776 us; speedup 1.0000x reference)
//
#include <hip/hip_runtime.h>
#include <math.h>

// CRF NLL: B=512 chains, L=1024 steps, T=48 tags.
// 1 wave per chain. Lane j<48 owns state-column j. Recursion in log2 domain.
// Per step: new2[j] = feat2[t][j] + M2 + log2( sum_i 2^(alpha2_i - M2) * E[i][j] ),
// E = exp(trans) pre-packed as half2 columns; inner product via v_dot2_f32_f16
// with p-pairs broadcast from even lanes (24 readlane + 24 dot2).

constexpr int Bn = 512;
constexpr int Ln = 1024;
constexpr int Tn = 48;

typedef _Float16 half2_t __attribute__((ext_vector_type(2)));

#define DPP_MAX(x, ctrl)                                                      \
  x = fmaxf(x, __int_as_float(__builtin_amdgcn_update_dpp(                    \
                  __float_as_int(x), __float_as_int(x), (ctrl), 0xf, 0xf, false)))

// max over all 64 lanes, broadcast via readlane (lanes 48-63 must hold -inf)
__device__ __forceinline__ float wave_max_bcast(float x) {
  DPP_MAX(x, 0x111);  // row_shr:1
  DPP_MAX(x, 0x112);  // row_shr:2
  DPP_MAX(x, 0x114);  // row_shr:4
  DPP_MAX(x, 0x118);  // row_shr:8
  DPP_MAX(x, 0x142);  // row_bcast:15
  DPP_MAX(x, 0x143);  // row_bcast:31
  return __int_as_float(__builtin_amdgcn_readlane(__float_as_int(x), 63));
}

extern "C" __global__ void __launch_bounds__(64)
crf_fwd(const float* __restrict__ feats, const float* __restrict__ trans,
        const float* __restrict__ startt, const float* __restrict__ endt,
        const int* __restrict__ tags, const int* __restrict__ mask,
        float* __restrict__ out) {
  const int b = blockIdx.x;
  const int lane = threadIdx.x;
  const int* tagr = tags + b * Ln;
  const int* maskr = mask + b * Ln;
  const float* frow = feats + (size_t)b * Ln * Tn;

  const float LOG2E = 1.44269504088896340736f;
  const float LN2 = 0.69314718055994530942f;

  // ---- sequence length n = sum(mask row); mask is a prefix mask ----
  int n = 0;
#pragma unroll
  for (int k = 0; k < Ln / 64; ++k) n += maskr[lane + 64 * k];
#pragma unroll
  for (int o = 32; o > 0; o >>= 1) n += __shfl_xor(n, o, 64);
  // n is wave-uniform now (n >= L/2 = 512 by construction)

  // ---- gold score (natural-log domain) ----
  float gold = 0.f;
#pragma unroll 4
  for (int k = 0; k < Ln / 64; ++k) {
    int l = lane + 64 * k;
    int tl = tagr[l];
    float c = frow[l * Tn + tl];
    if (l == 0)
      c += startt[tl];
    else
      c += trans[tagr[l - 1] * Tn + tl];
    gold += (l < n) ? c : 0.f;
  }
#pragma unroll
  for (int o = 32; o > 0; o >>= 1) gold += __shfl_xor(gold, o, 64);
  gold += endt[tagr[n - 1]];

  // ---- precompute E column j as half2 pairs: Ehpk[k] = (E[2k][j], E[2k+1][j]) ----
  const int j = (lane < Tn) ? lane : 0;
  half2_t Ehpk[Tn / 2];
#pragma unroll
  for (int k = 0; k < Tn / 2; ++k) {
    float e0 = exp2f(trans[(2 * k + 0) * Tn + j] * LOG2E);
    float e1 = exp2f(trans[(2 * k + 1) * Tn + j] * LOG2E);
    Ehpk[k][0] = (_Float16)e0;
    Ehpk[k][1] = (_Float16)e1;
  }

  // ---- forward scan (log2 domain) ----
  float alpha = (lane < Tn) ? ((startt[j] + frow[j]) * LOG2E) : -INFINITY;

  // 2-deep register prefetch of feats rows, pre-scaled by log2e
  float f0 = frow[Tn + j] * LOG2E;
  float f1 = frow[2 * Tn + j] * LOG2E;

  for (int t = 1; t < n; ++t) {
    float cur = f0;
    f0 = f1;
    int tp = (t + 2 < Ln) ? (t + 2) : (Ln - 1);  // clamp: harmless re-read
    f1 = frow[tp * Tn + j] * LOG2E;

    float M = wave_max_bcast(alpha);  // exact max -> p <= 1, f16-safe
    float p = exp2f(alpha - M);       // lanes>=48: exp2(-inf)=0

    // p from lane+1 via DPP row_shl:1 (lanes 15/31/47 keep old value; their
    // pairs are never consumed -- readlane only reads even lanes 0..46).
    float pnb = __int_as_float(__builtin_amdgcn_update_dpp(
        __float_as_int(p), __float_as_int(p), 0x101, 0xf, 0xf, false));
    auto pk2 = __builtin_amdgcn_cvt_pkrtz(p, pnb);  // (p_m, p_{m+1}), __fp16x2
    int pkb = __builtin_bit_cast(int, pk2);

    float a0 = 0.f, a1 = 0.f, a2 = 0.f, a3 = 0.f;
#pragma unroll
    for (int k = 0; k < Tn / 2; k += 4) {
      a0 = __builtin_amdgcn_fdot2(
          __builtin_bit_cast(half2_t, __builtin_amdgcn_readlane(pkb, 2 * k + 0)),
          Ehpk[k + 0], a0, false);
      a1 = __builtin_amdgcn_fdot2(
          __builtin_bit_cast(half2_t, __builtin_amdgcn_readlane(pkb, 2 * k + 2)),
          Ehpk[k + 1], a1, false);
      a2 = __builtin_amdgcn_fdot2(
          __builtin_bit_cast(half2_t, __builtin_amdgcn_readlane(pkb, 2 * k + 4)),
          Ehpk[k + 2], a2, false);
      a3 = __builtin_amdgcn_fdot2(
          __builtin_bit_cast(half2_t, __builtin_amdgcn_readlane(pkb, 2 * k + 6)),
          Ehpk[k + 3], a3, false);
    }
    float s = (a0 + a1) + (a2 + a3);
    float an = cur + M + log2f(s);
    alpha = (lane < Tn) ? an : -INFINITY;
  }

  // ---- fwd = logsumexp(alpha + end), converted back to natural log ----
  float v = (lane < Tn) ? (alpha + endt[j] * LOG2E) : -INFINITY;
  float M = wave_max_bcast(v);
  float e = (lane < Tn) ? exp2f(v - M) : 0.f;
#pragma unroll
  for (int o = 32; o > 0; o >>= 1) e += __shfl_xor(e, o, 64);
  float fwd = (M + log2f(e)) * LN2;

  if (lane == 0) atomicAdd(out, fwd - gold);
}

extern "C" void kernel_launch(void* const* d_in, const int* in_sizes, int n_in,
                              void* d_out, int out_size, void* d_ws, size_t ws_size,
                              hipStream_t stream) {
  const float* feats = (const float*)d_in[0];
  const float* trans = (const float*)d_in[1];
  const float* startt = (const float*)d_in[2];
  const float* endt = (const float*)d_in[3];
  const int* tags = (const int*)d_in[4];
  const int* mask = (const int*)d_in[5];
  float* out = (float*)d_out;

  (void)hipMemsetAsync(out, 0, sizeof(float), stream);
  crf_fwd<<<dim3(Bn), dim3(64), 0, stream>>>(feats, trans, startt, endt, tags,
                                             mask, out);
}